// Round 15
// baseline (1062.809 us; speedup 1.0000x reference)
//
#include <hip/hip_runtime.h>

typedef unsigned short u16;
typedef __attribute__((ext_vector_type(8))) short short8;
typedef __attribute__((ext_vector_type(4))) float f32x4;
typedef __attribute__((ext_vector_type(16))) float f32x16;
typedef const __attribute__((address_space(1))) void* gas_p;
typedef __attribute__((address_space(3))) void* las_p;

// ---------- constants ----------
#define LL (6)
#define BB (4)
#define TT (1024)
#define EE (512)
#define HH (8)
#define HD (64)
#define T4 (256)
#define FF (2048)
#define BT (BB*TT)           // 4096
#define LAMBDA (0.001f)

// ---------- helpers ----------
struct Off3 { long long hi, lo; int mod; };
__device__ __forceinline__ long long off3(Off3 o, int z) {
  return (long long)(z / o.mod) * o.hi + (long long)(z % o.mod) * o.lo;
}
__device__ __forceinline__ float b2f(u16 u) { return __uint_as_float((unsigned)u << 16); }
__device__ __forceinline__ u16 f2b(float f) {
  unsigned u = __float_as_uint(f);
  return (u16)((u + 0x7fffu + ((u >> 16) & 1u)) >> 16);   // RNE
}
__device__ __forceinline__ float tof(float v) { return v; }
__device__ __forceinline__ float tof(u16 v) { return b2f(v); }

// ---------- pipelined MFMA GEMM: C = act(alpha * A @ Bt^T + bias) ----------
// BK=64, double-buffered LDS; stage(next) before compute(cur); 1 barrier/K-step.
// QKV mode: N=1536 cols = q|k|v; q row-major, k/v transposed per head.
template<int BM, int BN, bool C_BF16, int ACT, bool SPLITK, bool QKV>
__global__ __launch_bounds__(256) void gemm_p(
    const u16* __restrict__ A, const u16* __restrict__ Bt, void* __restrict__ Cv,
    const float* __restrict__ bias, float alpha,
    int K, int lda, int ldb, int ldc,
    Off3 oa, Off3 ob, Off3 oc, Off3 obias, long long sstride,
    u16* __restrict__ kTo, u16* __restrict__ vTo)
{
  constexpr int BK = 64;
  constexpr int WM = BM / 2, WN = BN / 2;
  constexpr int MR = WM / 16, NR = WN / 16;
  __shared__ alignas(16) u16 lA[2][BM * BK];
  __shared__ alignas(16) u16 lB[2][BN * BK];

  const int z = blockIdx.z;
  A  += off3(oa, z);
  Bt += off3(ob, z);
  long long cb = off3(oc, z);
  long long bn;
  if constexpr (SPLITK) {
    const long long kb = (long long)blockIdx.y * K;
    A += kb; Bt += kb;
    cb += (long long)blockIdx.y * sstride;
    bn = 0;
  } else {
    bn = (long long)blockIdx.y * BN;
  }
  const int tid = threadIdx.x;
  const int lane = tid & 63, wave = tid >> 6;
  const int wm = wave >> 1, wn = wave & 1;
  const int l15 = lane & 15, g = lane >> 4;
  const long long bm = (long long)blockIdx.x * BM;

#define STAGE(buf, k0)                                                          \
  {                                                                             \
    _Pragma("unroll")                                                           \
    for (int j = 0; j < (BM * 8) / 256; ++j) {                                  \
      const int c = j * 256 + tid, row = c >> 3, slot = c & 7;                  \
      const u16* src = A + (bm + row) * (long long)lda + (k0) +                 \
                       ((slot ^ (row & 7)) << 3);                               \
      __builtin_amdgcn_global_load_lds((gas_p)src, (las_p)(&lA[buf][c * 8]), 16, 0, 0); \
    }                                                                           \
    _Pragma("unroll")                                                           \
    for (int j = 0; j < (BN * 8) / 256; ++j) {                                  \
      const int c = j * 256 + tid, row = c >> 3, slot = c & 7;                  \
      const u16* src = Bt + (bn + row) * (long long)ldb + (k0) +                \
                       ((slot ^ (row & 7)) << 3);                               \
      __builtin_amdgcn_global_load_lds((gas_p)src, (las_p)(&lB[buf][c * 8]), 16, 0, 0); \
    }                                                                           \
  }

  f32x4 acc[MR][NR] = {};
  STAGE(0, 0);
  __syncthreads();
  int cur = 0;
  for (int k0 = 0; k0 < K; k0 += BK) {
    if (k0 + BK < K) STAGE(cur ^ 1, k0 + BK);
    #pragma unroll
    for (int kk = 0; kk < 2; ++kk) {
      short8 af[MR], bfr[NR];
      #pragma unroll
      for (int m = 0; m < MR; ++m) {
        const int row = wm * WM + m * 16 + l15;
        af[m] = *(const short8*)(&lA[cur][row * BK + ((((kk << 2) + g) ^ (row & 7)) << 3)]);
      }
      #pragma unroll
      for (int n = 0; n < NR; ++n) {
        const int row = wn * WN + n * 16 + l15;
        bfr[n] = *(const short8*)(&lB[cur][row * BK + ((((kk << 2) + g) ^ (row & 7)) << 3)]);
      }
      #pragma unroll
      for (int m = 0; m < MR; ++m)
        #pragma unroll
        for (int n = 0; n < NR; ++n)
          acc[m][n] = __builtin_amdgcn_mfma_f32_16x16x32_bf16(af[m], bfr[n], acc[m][n], 0, 0, 0);
    }
    __syncthreads();
    cur ^= 1;
  }
#undef STAGE

  const float* bp = bias ? (bias + off3(obias, z)) : nullptr;
  if constexpr (QKV) {
    #pragma unroll
    for (int m = 0; m < MR; ++m) {
      const long long row0 = bm + wm * WM + m * 16 + g * 4;
      const int b = (int)(row0 >> 10), tt = (int)(row0 & 1023);
      #pragma unroll
      for (int n = 0; n < NR; ++n) {
        const int col = (int)(bn + wn * WN + n * 16 + l15);
        const float bv = bp[col];
        const int sec = col >> 9, d = col & 511;
        u16 vb[4];
        #pragma unroll
        for (int r = 0; r < 4; ++r) vb[r] = f2b(acc[m][n][r] + bv);
        if (sec == 0) {
          #pragma unroll
          for (int r = 0; r < 4; ++r)
            ((u16*)Cv)[(row0 + r) * 512 + d] = vb[r];
        } else {
          u16* dst = (sec == 1 ? kTo : vTo);
          ushort4 p4; p4.x = vb[0]; p4.y = vb[1]; p4.z = vb[2]; p4.w = vb[3];
          *(ushort4*)(dst + (size_t)(b * 8 + (d >> 6)) * 65536 + (size_t)(d & 63) * 1024 + tt) = p4;
        }
      }
    }
  } else {
    #pragma unroll
    for (int m = 0; m < MR; ++m) {
      const long long row0 = bm + wm * WM + m * 16 + g * 4;
      #pragma unroll
      for (int n = 0; n < NR; ++n) {
        const long long col = bn + wn * WN + n * 16 + l15;
        const float bv = bp ? bp[col] : 0.0f;
        #pragma unroll
        for (int r = 0; r < 4; ++r) {
          float v = acc[m][n][r] * alpha + bv;
          if (ACT == 1) v = fmaxf(v, 0.0f);
          const long long idx = cb + (row0 + r) * (long long)ldc + col;
          if constexpr (C_BF16) ((u16*)Cv)[idx] = f2b(v);
          else                  ((float*)Cv)[idx] = v;
        }
      }
    }
  }
}

// ---------- sum 4 split-K partials -> bf16 ----------
__global__ __launch_bounds__(256) void mt_combine_kernel(
    const float* __restrict__ part, u16* __restrict__ out)
{
  const int i = blockIdx.x * 256 + threadIdx.x;
  const float s = part[i] + part[i + 524288] + part[i + 2 * 524288] + part[i + 3 * 524288];
  out[i] = f2b(s);
}

// ---------- fused attention tail (v7: 4-wave blocks, sp=4, bf16 partials) ----------
// 1D grid 1024: id = h8(3) | tb(3) | sp(2) | b(2). XCD pin via h8 = id&7.
// Block: 256 threads = 4 waves, each wave owns 32 t (t = tb*128 + wave*32 + l31).
// Phase 0: lat = relu(0.125*q@MT^T + be) via mfma32 (q, MT from L2), C-frag ->
//          B-frag via cvt_pk + shfl_xor(32).
// Loop: 8 chunks of 32 s; rec P^T = mfma32(wd_frag, latf); pe = exp(sigmoid(.+bd));
//       PV A-frag in-register; v B-frags direct from L2. Partials stored bf16.
__global__ __launch_bounds__(256, 3) void attn_tail_kernel(
    const u16* __restrict__ q, const u16* __restrict__ MT,
    const float* __restrict__ be, const u16* __restrict__ wdT,
    const float* __restrict__ bd, const u16* __restrict__ vT,
    u16* __restrict__ o_part, float* __restrict__ rs_part)
{
  __shared__ alignas(16) u16 wdL[2][32 * 256];   // 2 x 16 KB: [s:32][u:256]
  const int id = blockIdx.x;
  const int h8 = id & 7;
  const int tb = (id >> 3) & 7;
  const int sp = (id >> 6) & 3;
  const int b  = id >> 8;
  const int z  = b * 8 + h8;
  const int lane = threadIdx.x & 63, wave = threadIdx.x >> 6;  // wave 0..3
  const int l31 = lane & 31, h = lane >> 5;
  const int s0 = sp * 256;
  const u16* wdh  = wdT + (size_t)h8 * 262144;
  const float* bdh = bd + (size_t)h8 * 1024 + s0;
  const u16* vz = vT + (size_t)z * 65536 + s0;    // [d:64][s:1024] + s0

#define ASTAGE(buf, sc)                                                          \
  {                                                                              \
    const int sb_ = (sc) * 32;                                                   \
    _Pragma("unroll")                                                            \
    for (int j = 0; j < 4; ++j) {                                                \
      const int c = j * 256 + threadIdx.x;                                       \
      const int row = c >> 5, slot = c & 31;                                     \
      __builtin_amdgcn_global_load_lds(                                          \
          (gas_p)(wdh + (size_t)(s0 + sb_ + row) * 256 + ((slot ^ (row & 7)) << 3)), \
          (las_p)(&wdL[buf][c * 8]), 16, 0, 0);                                  \
    }                                                                            \
  }

  ASTAGE(0, 0);     // wd chunk 0 in flight while lat computes below

  // ---- phase 0: lat in registers ----
  // B-op (q): col t, k = d; A-op (MT): row u, k = d.
  short8 latf[16];
  {
    const int t = tb * 128 + wave * 32 + l31;
    const u16* qp = q + ((size_t)b * 1024 + t) * 512 + h8 * 64 + h * 8;
    const u16* mtp = MT + (size_t)z * 16384 + (size_t)l31 * 64 + h * 8;
    const float* beh = be + h8 * 256;
    short8 qf[4];
    #pragma unroll
    for (int kd = 0; kd < 4; ++kd) qf[kd] = *(const short8*)(qp + kd * 16);
    #pragma unroll
    for (int ublk = 0; ublk < 8; ++ublk) {
      f32x16 lacc = {};
      #pragma unroll
      for (int kd = 0; kd < 4; ++kd) {
        const short8 mtf = *(const short8*)(mtp + ublk * 2048 + kd * 16);
        lacc = __builtin_amdgcn_mfma_f32_32x32x16_bf16(mtf, qf[kd], lacc, 0, 0, 0);
      }
      float pe[16];
      #pragma unroll
      for (int q4 = 0; q4 < 4; ++q4) {
        const float4 b4 = *(const float4*)(beh + ublk * 32 + q4 * 8 + 4 * h);
        #pragma unroll
        for (int r2 = 0; r2 < 4; ++r2)
          pe[q4 * 4 + r2] = fmaxf(lacc[q4 * 4 + r2] * 0.125f + ((const float*)&b4)[r2], 0.0f);
      }
      unsigned w[8];
      #pragma unroll
      for (int i = 0; i < 8; ++i)
        asm("v_cvt_pk_bf16_f32 %0, %1, %2" : "=v"(w[i]) : "v"(pe[2 * i]), "v"(pe[2 * i + 1]));
      // kg even: u%32 in [0,16)
      {
        const unsigned sA = h ? w[0] : w[2];
        const unsigned rA = (unsigned)__shfl_xor((int)sA, 32);
        const unsigned sB = h ? w[1] : w[3];
        const unsigned rB = (unsigned)__shfl_xor((int)sB, 32);
        short8 f;
        ((unsigned*)&f)[0] = h ? rA : w[0];
        ((unsigned*)&f)[1] = h ? rB : w[1];
        ((unsigned*)&f)[2] = h ? w[2] : rA;
        ((unsigned*)&f)[3] = h ? w[3] : rB;
        latf[2 * ublk] = f;
      }
      // kg odd: u%32 in [16,32)
      {
        const unsigned sA = h ? w[4] : w[6];
        const unsigned rA = (unsigned)__shfl_xor((int)sA, 32);
        const unsigned sB = h ? w[5] : w[7];
        const unsigned rB = (unsigned)__shfl_xor((int)sB, 32);
        short8 f;
        ((unsigned*)&f)[0] = h ? rA : w[4];
        ((unsigned*)&f)[1] = h ? rB : w[5];
        ((unsigned*)&f)[2] = h ? w[6] : rA;
        ((unsigned*)&f)[3] = h ? w[7] : rB;
        latf[2 * ublk + 1] = f;
      }
    }
  }

  f32x16 oacc[2] = {};
  float rsum = 0.f;

  __syncthreads();   // wd chunk 0 staged
  int cur = 0;
  for (int sc = 0; sc < 8; ++sc) {
    if (sc < 7) ASTAGE(cur ^ 1, sc + 1);
    const int sb = sc * 32;

    // hoist v B-frags for both k2 halves (L2-resident; latency hides under rec+exp)
    short8 vb[2][2];
    #pragma unroll
    for (int k2 = 0; k2 < 2; ++k2)
      #pragma unroll
      for (int nd = 0; nd < 2; ++nd)
        vb[k2][nd] = *(const short8*)(vz + (size_t)(nd * 32 + l31) * 1024 + sb + k2 * 16 + 8 * h);

    // rec: pacc = P^T frag (s' = (r&3)+8(r>>2)+4h, t = l31)
    f32x16 pacc = {};
    #pragma unroll
    for (int kg = 0; kg < 16; ++kg) {
      const short8 a = *(const short8*)(&wdL[cur][l31 * 256 + (((kg * 2 + h) ^ (l31 & 7)) << 3)]);
      pacc = __builtin_amdgcn_mfma_f32_32x32x16_bf16(a, latf[kg], pacc, 0, 0, 0);
    }

    // per 16-s half: epilogue + in-register P rebuild + PV
    #pragma unroll
    for (int k2 = 0; k2 < 2; ++k2) {
      float pe[8];
      #pragma unroll
      for (int p4 = 0; p4 < 2; ++p4) {
        const int pp = k2 * 2 + p4;
        const float4 b4 = *(const float4*)(bdh + sb + pp * 8 + 4 * h);
        #pragma unroll
        for (int qq = 0; qq < 4; ++qq) {
          const float val = pacc[pp * 4 + qq] + ((const float*)&b4)[qq];
          const float sig = 1.0f / (1.0f + __expf(-val));
          pe[p4 * 4 + qq] = __expf(sig);
          rsum += pe[p4 * 4 + qq];
        }
      }
      unsigned wloA, wloB, whiA, whiB;
      asm("v_cvt_pk_bf16_f32 %0, %1, %2" : "=v"(wloA) : "v"(pe[0]), "v"(pe[1]));
      asm("v_cvt_pk_bf16_f32 %0, %1, %2" : "=v"(wloB) : "v"(pe[2]), "v"(pe[3]));
      asm("v_cvt_pk_bf16_f32 %0, %1, %2" : "=v"(whiA) : "v"(pe[4]), "v"(pe[5]));
      asm("v_cvt_pk_bf16_f32 %0, %1, %2" : "=v"(whiB) : "v"(pe[6]), "v"(pe[7]));
      const unsigned xA = h ? wloA : whiA;
      const unsigned rA = (unsigned)__shfl_xor((int)xA, 32);
      const unsigned xB = h ? wloB : whiB;
      const unsigned rB = (unsigned)__shfl_xor((int)xB, 32);
      short8 pa;
      ((unsigned*)&pa)[0] = h ? rA : wloA;
      ((unsigned*)&pa)[1] = h ? rB : wloB;
      ((unsigned*)&pa)[2] = h ? whiA : rA;
      ((unsigned*)&pa)[3] = h ? whiB : rB;
      #pragma unroll
      for (int nd = 0; nd < 2; ++nd)
        oacc[nd] = __builtin_amdgcn_mfma_f32_32x32x16_bf16(pa, vb[k2][nd], oacc[nd], 0, 0, 0);
    }
    __syncthreads();
    cur ^= 1;
  }
#undef ASTAGE

  rsum += __shfl_xor(rsum, 32);
  const long long orow0 = (long long)b * 1024 + tb * 128 + wave * 32;
  u16* op = o_part + (size_t)sp * ((size_t)BT * EE);
  #pragma unroll
  for (int nd = 0; nd < 2; ++nd)
    #pragma unroll
    for (int r = 0; r < 16; ++r) {
      const int trow = (r & 3) + 8 * (r >> 2) + 4 * h;
      op[(orow0 + trow) * 512 + h8 * 64 + nd * 32 + l31] = f2b(oacc[nd][r]);
    }
  if (h == 0)
    rs_part[(size_t)sp * 32768 + (size_t)z * 1024 + tb * 128 + wave * 32 + l31] = rsum;
}

// ---------- combine partials: o = (Σ o_p) / (Σ rs_p), bf16 ----------
__global__ __launch_bounds__(256) void attn_combine_kernel(
    const u16* __restrict__ o_part, const float* __restrict__ rs_part,
    u16* __restrict__ o)
{
  const int row = blockIdx.x;
  const int b = row >> 10, t = row & 1023;
  #pragma unroll
  for (int j = 0; j < 2; ++j) {
    const int c = j * 256 + threadIdx.x;
    const int bh = b * 8 + (c >> 6);
    float rs = 0.f, v = 0.f;
    #pragma unroll
    for (int p = 0; p < 4; ++p) {
      rs += rs_part[(size_t)p * 32768 + (size_t)bh * 1024 + t];
      v  += b2f(o_part[(size_t)p * BT * EE + (size_t)row * 512 + c]);
    }
    o[(size_t)row * 512 + c] = f2b(v / rs);
  }
}

// ---------- embedding ----------
__global__ __launch_bounds__(256) void embed_kernel(
    const float* __restrict__ tok, const float* __restrict__ pos,
    const int* __restrict__ x, float* __restrict__ h, u16* __restrict__ hb)
{
  const long long row = blockIdx.x;
  const int t = (int)(row & (TT - 1));
  const long long tokid = x[row];
  const float* te = tok + tokid * EE;
  const float* pe = pos + (long long)t * EE;
  const long long base = row * EE;
  for (int e = threadIdx.x; e < EE; e += 256) {
    float v = te[e] + pe[e];
    h[base + e] = v;
    hb[base + e] = f2b(v);
  }
}

// ---------- residual + layernorm (bf16 delta) ----------
__global__ __launch_bounds__(256) void addnorm_kernel(
    const float* __restrict__ hin, const u16* __restrict__ delta,
    const float* __restrict__ g, const float* __restrict__ bta,
    float* __restrict__ hout, u16* __restrict__ hbout)
{
  __shared__ float sm[8];
  const long long base = (long long)blockIdx.x * EE;
  const int tid = threadIdx.x;
  float x0 = hin[base + tid] + b2f(delta[base + tid]);
  float x1 = hin[base + tid + 256] + b2f(delta[base + tid + 256]);
  float s = x0 + x1, ss = x0 * x0 + x1 * x1;
  #pragma unroll
  for (int o = 32; o; o >>= 1) { s += __shfl_down(s, o); ss += __shfl_down(ss, o); }
  if ((tid & 63) == 0) { sm[tid >> 6] = s; sm[4 + (tid >> 6)] = ss; }
  __syncthreads();
  const float S = sm[0] + sm[1] + sm[2] + sm[3];
  const float SS = sm[4] + sm[5] + sm[6] + sm[7];
  const float mu = S * (1.0f / EE);
  const float var = SS * (1.0f / EE) - mu * mu;
  const float inv = rsqrtf(var + 1e-5f);
  const float y0 = (x0 - mu) * inv * g[tid] + bta[tid];
  const float y1 = (x1 - mu) * inv * g[tid + 256] + bta[tid + 256];
  hout[base + tid] = y0;       hout[base + tid + 256] = y1;
  hbout[base + tid] = f2b(y0); hbout[base + tid + 256] = f2b(y1);
}

// ---------- LDS-tiled transpose-convert ----------
template<typename ST>
__global__ __launch_bounds__(256) void transposeT_kernel(
    u16* __restrict__ dst, const ST* __restrict__ src,
    int ldsrc, int lddst, Off3 dstz, Off3 srcz)
{
  __shared__ float t[32][33];
  const int z = blockIdx.z;
  const ST* s = src + off3(srcz, z);
  u16* d = dst + off3(dstz, z);
  const int r0 = blockIdx.x * 32, c0 = blockIdx.y * 32;
  const int tx = threadIdx.x & 31, ty = threadIdx.x >> 5;
  #pragma unroll
  for (int j = 0; j < 4; ++j) {
    const int r = ty + j * 8;
    t[r][tx] = tof(s[(long long)(r0 + r) * ldsrc + c0 + tx]);
  }
  __syncthreads();
  #pragma unroll
  for (int j = 0; j < 4; ++j) {
    const int c = ty + j * 8;
    d[(long long)(c0 + c) * lddst + r0 + tx] = f2b(t[tx][c]);
  }
}

// ---------- stack bq|bk|bv per layer ----------
__global__ __launch_bounds__(256) void biaspack_kernel(
    float* __restrict__ dst, const float* __restrict__ bq,
    const float* __restrict__ bk, const float* __restrict__ bv)
{
  const int i = blockIdx.x * 256 + threadIdx.x;
  if (i >= LL * 1536) return;
  const int l = i / 1536, j = i % 1536;
  dst[i] = (j < 512) ? bq[l * 512 + j]
         : (j < 1024) ? bk[l * 512 + j - 512]
                      : bv[l * 512 + j - 1024];
}

__global__ void finalize_loss(float* out) { out[0] = LAMBDA * (float)(LL * 32 * 1024); }

// ---------- host ----------
extern "C" void kernel_launch(void* const* d_in, const int* in_sizes, int n_in,
                              void* d_out, int out_size, void* d_ws, size_t ws_size,
                              hipStream_t stream)
{
  (void)in_sizes; (void)n_in; (void)out_size; (void)ws_size;
  const float* tok = (const float*)d_in[0];
  const float* pos = (const float*)d_in[1];
  const float* wq  = (const float*)d_in[2];
  const float* bq  = (const float*)d_in[3];
  const float* wk  = (const float*)d_in[4];
  const float* bk  = (const float*)d_in[5];
  const float* wv  = (const float*)d_in[6];
  const float* bv  = (const float*)d_in[7];
  const float* we  = (const float*)d_in[8];
  const float* be  = (const float*)d_in[9];
  const float* wd  = (const float*)d_in[10];
  const float* bd  = (const float*)d_in[11];
  const float* wo  = (const float*)d_in[12];
  const float* bo  = (const float*)d_in[13];
  const float* ln1g = (const float*)d_in[14];
  const float* ln1b = (const float*)d_in[15];
  const float* w1  = (const float*)d_in[16];
  const float* b1  = (const float*)d_in[17];
  const float* w2  = (const float*)d_in[18];
  const float* b2  = (const float*)d_in[19];
  const float* ln2g = (const float*)d_in[20];
  const float* ln2b = (const float*)d_in[21];
  const int*   x   = (const int*)d_in[22];

  char* ws = (char*)d_ws;
  size_t off = 0;
  auto alloc = [&](size_t bytes) { void* p = ws + off; off = (off + bytes + 255) & ~255ULL; return p; };

  u16*  wqkvT = (u16*)alloc((size_t)LL * 3 * 512 * 512 * 2);
  u16*  weT   = (u16*)alloc((size_t)LL * HH * T4 * TT * 2);
  u16*  wdT   = (u16*)alloc((size_t)LL * HH * TT * T4 * 2);
  u16*  woT   = (u16*)alloc((size_t)LL * EE * EE * 2);
  u16*  w1T   = (u16*)alloc((size_t)LL * FF * EE * 2);
  u16*  w2T   = (u16*)alloc((size_t)LL * EE * FF * 2);
  float* bqkv = (float*)alloc((size_t)LL * 1536 * 4);
  float* h_f  = (float*)alloc((size_t)BT * EE * 4);
  u16*  h_b   = (u16*)alloc((size_t)BT * EE * 2);
  u16*  q_b   = (u16*)alloc((size_t)BT * EE * 2);
  u16*  kT_b  = (u16*)alloc((size_t)32 * HD * TT * 2);
  u16*  vT_b  = (u16*)alloc((size_t)32 * HD * TT * 2);
  u16*  MT_b  = (u16*)alloc((size_t)32 * T4 * HD * 2);
  float* MT_part = (float*)alloc((size_t)4 * 32 * T4 * HD * 4);
  u16*  o_b   = (u16*)alloc((size_t)BT * EE * 2);
  u16*  attn_d = (u16*)alloc((size_t)BT * EE * 2);
  u16*  ff2_d  = (u16*)alloc((size_t)BT * EE * 2);
  u16*  ff1_b = (u16*)alloc((size_t)BT * FF * 2);
  u16*  o_part = (u16*)alloc((size_t)4 * BT * EE * 2);
  float* rs_part = (float*)alloc((size_t)4 * 32 * 1024 * 4);

  const Off3 Z1 = {0, 0, 1};

  embed_kernel<<<dim3(BT), 256, 0, stream>>>(tok, pos, x, h_f, h_b);
  biaspack_kernel<<<dim3((LL * 1536 + 255) / 256), 256, 0, stream>>>(bqkv, bq, bk, bv);

  transposeT_kernel<float><<<dim3(16, 2, 48), 256, 0, stream>>>(
      wqkvT,          wq, 64, 512, Off3{786432, 32768, 8}, Off3{32768, 0, 1});
  transposeT_kernel<float><<<dim3(16, 2, 48), 256, 0, stream>>>(
      wqkvT + 262144, wk, 64, 512, Off3{786432, 32768, 8}, Off3{32768, 0, 1});
  transposeT_kernel<float><<<dim3(16, 2, 48), 256, 0, stream>>>(
      wqkvT + 524288, wv, 64, 512, Off3{786432, 32768, 8}, Off3{32768, 0, 1});
  transposeT_kernel<float><<<dim3(32, 8, 48), 256, 0, stream>>>(
      weT, we, 256, 1024, Off3{262144, 0, 1}, Off3{262144, 0, 1});
  transposeT_kernel<float><<<dim3(8, 32, 48), 256, 0, stream>>>(
      wdT, wd, 1024, 256, Off3{262144, 0, 1}, Off3{262144, 0, 1});
  transposeT_kernel<float><<<dim3(16, 16, 6), 256, 0, stream>>>(
      woT, wo, 512, 512, Off3{262144, 0, 1}, Off3{262144, 0, 1});
  transposeT_kernel<float><<<dim3(16, 64, 6), 256, 0, stream>>>(
      w1T, w1, 2048, 512, Off3{1048576, 0, 1}, Off3{1048576, 0, 1});
  transposeT_kernel<float><<<dim3(64, 16, 6), 256, 0, stream>>>(
      w2T, w2, 512, 2048, Off3{1048576, 0, 1}, Off3{1048576, 0, 1});

  for (int l = 0; l < LL; ++l) {
    // --- fused q|k|v projection; q row-major, k/v transposed per head ---
    gemm_p<64, 128, true, 0, false, true><<<dim3(64, 12, 1), 256, 0, stream>>>(
        h_b, wqkvT + (size_t)l * 786432, q_b, bqkv + l * 1536, 1.0f,
        512, 512, 512, 512, Z1, Z1, Z1, Z1, 0, kT_b, vT_b);

    // --- MT[u][d] = sum_s we[s][u] k[s][d] : split-K x4 ---
    gemm_p<64, 64, false, 0, true, false><<<dim3(4, 4, 32), 256, 0, stream>>>(
        weT + (size_t)l * 2097152, kT_b, MT_part, nullptr, 1.0f,
        256, 1024, 1024, 64,
        Off3{0, 262144, 8}, Off3{65536, 0, 1}, Off3{16384, 0, 1}, Z1, 524288,
        nullptr, nullptr);
    mt_combine_kernel<<<dim3(2048), 256, 0, stream>>>(MT_part, MT_b);

    // --- fused tail: lat in-register; P = exp(sigmoid(lat@wd+bd)); bf16 partials ---
    attn_tail_kernel<<<dim3(1024), 256, 0, stream>>>(
        q_b, MT_b, be + (size_t)l * 2048, wdT + (size_t)l * 2097152,
        bd + (size_t)l * 8192, vT_b, o_part, rs_part);
    attn_combine_kernel<<<dim3(BT), 256, 0, stream>>>(o_part, rs_part, o_b);

    // --- attn out projection ---
    gemm_p<64, 64, true, 0, false, false><<<dim3(64, 8, 1), 256, 0, stream>>>(
        o_b, woT + (size_t)l * 262144, attn_d, bo + l * 512, 1.0f,
        512, 512, 512, 512, Z1, Z1, Z1, Z1, 0, nullptr, nullptr);

    addnorm_kernel<<<dim3(BT), 256, 0, stream>>>(h_f, attn_d, ln1g + l * 512, ln1b + l * 512, h_f, h_b);

    // --- FFN ---
    gemm_p<64, 128, true, 1, false, false><<<dim3(64, 16, 1), 256, 0, stream>>>(
        h_b, w1T + (size_t)l * 1048576, ff1_b, b1 + l * 2048, 1.0f,
        512, 512, 512, 2048, Z1, Z1, Z1, Z1, 0, nullptr, nullptr);
    gemm_p<64, 64, true, 1, false, false><<<dim3(64, 8, 1), 256, 0, stream>>>(
        ff1_b, w2T + (size_t)l * 1048576, ff2_d, b2 + l * 512, 1.0f,
        2048, 2048, 2048, 512, Z1, Z1, Z1, Z1, 0, nullptr, nullptr);

    float* hout = (l == LL - 1) ? (float*)d_out : h_f;
    addnorm_kernel<<<dim3(BT), 256, 0, stream>>>(h_f, ff2_d, ln2g + l * 512, ln2b + l * 512, hout, h_b);
  }

  finalize_loss<<<1, 1, 0, stream>>>((float*)d_out + (size_t)BT * EE);
}

// Round 16
// 992.298 us; speedup vs baseline: 1.0711x; 1.0711x over previous
//
#include <hip/hip_runtime.h>

typedef unsigned short u16;
typedef __attribute__((ext_vector_type(8))) short short8;
typedef __attribute__((ext_vector_type(4))) float f32x4;
typedef __attribute__((ext_vector_type(16))) float f32x16;
typedef const __attribute__((address_space(1))) void* gas_p;
typedef __attribute__((address_space(3))) void* las_p;

// ---------- constants ----------
#define LL (6)
#define BB (4)
#define TT (1024)
#define EE (512)
#define HH (8)
#define HD (64)
#define T4 (256)
#define FF (2048)
#define BT (BB*TT)           // 4096
#define LAMBDA (0.001f)

// ---------- helpers ----------
struct Off3 { long long hi, lo; int mod; };
__device__ __forceinline__ long long off3(Off3 o, int z) {
  return (long long)(z / o.mod) * o.hi + (long long)(z % o.mod) * o.lo;
}
__device__ __forceinline__ float b2f(u16 u) { return __uint_as_float((unsigned)u << 16); }
__device__ __forceinline__ u16 f2b(float f) {
  unsigned u = __float_as_uint(f);
  return (u16)((u + 0x7fffu + ((u >> 16) & 1u)) >> 16);   // RNE
}
__device__ __forceinline__ float tof(float v) { return v; }
__device__ __forceinline__ float tof(u16 v) { return b2f(v); }

// ---------- pipelined MFMA GEMM: C = act(alpha * A @ Bt^T + bias) ----------
// BK=64, double-buffered LDS; stage(next) before compute(cur); 1 barrier/K-step.
// QKV mode: N=1536 cols = q|k|v; q row-major, k/v transposed per head.
template<int BM, int BN, bool C_BF16, int ACT, bool SPLITK, bool QKV>
__global__ __launch_bounds__(256) void gemm_p(
    const u16* __restrict__ A, const u16* __restrict__ Bt, void* __restrict__ Cv,
    const float* __restrict__ bias, float alpha,
    int K, int lda, int ldb, int ldc,
    Off3 oa, Off3 ob, Off3 oc, Off3 obias, long long sstride,
    u16* __restrict__ kTo, u16* __restrict__ vTo)
{
  constexpr int BK = 64;
  constexpr int WM = BM / 2, WN = BN / 2;
  constexpr int MR = WM / 16, NR = WN / 16;
  __shared__ alignas(16) u16 lA[2][BM * BK];
  __shared__ alignas(16) u16 lB[2][BN * BK];

  const int z = blockIdx.z;
  A  += off3(oa, z);
  Bt += off3(ob, z);
  long long cb = off3(oc, z);
  long long bn;
  if constexpr (SPLITK) {
    const long long kb = (long long)blockIdx.y * K;
    A += kb; Bt += kb;
    cb += (long long)blockIdx.y * sstride;
    bn = 0;
  } else {
    bn = (long long)blockIdx.y * BN;
  }
  const int tid = threadIdx.x;
  const int lane = tid & 63, wave = tid >> 6;
  const int wm = wave >> 1, wn = wave & 1;
  const int l15 = lane & 15, g = lane >> 4;
  const long long bm = (long long)blockIdx.x * BM;

#define STAGE(buf, k0)                                                          \
  {                                                                             \
    _Pragma("unroll")                                                           \
    for (int j = 0; j < (BM * 8) / 256; ++j) {                                  \
      const int c = j * 256 + tid, row = c >> 3, slot = c & 7;                  \
      const u16* src = A + (bm + row) * (long long)lda + (k0) +                 \
                       ((slot ^ (row & 7)) << 3);                               \
      __builtin_amdgcn_global_load_lds((gas_p)src, (las_p)(&lA[buf][c * 8]), 16, 0, 0); \
    }                                                                           \
    _Pragma("unroll")                                                           \
    for (int j = 0; j < (BN * 8) / 256; ++j) {                                  \
      const int c = j * 256 + tid, row = c >> 3, slot = c & 7;                  \
      const u16* src = Bt + (bn + row) * (long long)ldb + (k0) +                \
                       ((slot ^ (row & 7)) << 3);                               \
      __builtin_amdgcn_global_load_lds((gas_p)src, (las_p)(&lB[buf][c * 8]), 16, 0, 0); \
    }                                                                           \
  }

  f32x4 acc[MR][NR] = {};
  STAGE(0, 0);
  __syncthreads();
  int cur = 0;
  for (int k0 = 0; k0 < K; k0 += BK) {
    if (k0 + BK < K) STAGE(cur ^ 1, k0 + BK);
    #pragma unroll
    for (int kk = 0; kk < 2; ++kk) {
      short8 af[MR], bfr[NR];
      #pragma unroll
      for (int m = 0; m < MR; ++m) {
        const int row = wm * WM + m * 16 + l15;
        af[m] = *(const short8*)(&lA[cur][row * BK + ((((kk << 2) + g) ^ (row & 7)) << 3)]);
      }
      #pragma unroll
      for (int n = 0; n < NR; ++n) {
        const int row = wn * WN + n * 16 + l15;
        bfr[n] = *(const short8*)(&lB[cur][row * BK + ((((kk << 2) + g) ^ (row & 7)) << 3)]);
      }
      #pragma unroll
      for (int m = 0; m < MR; ++m)
        #pragma unroll
        for (int n = 0; n < NR; ++n)
          acc[m][n] = __builtin_amdgcn_mfma_f32_16x16x32_bf16(af[m], bfr[n], acc[m][n], 0, 0, 0);
    }
    __syncthreads();
    cur ^= 1;
  }
#undef STAGE

  const float* bp = bias ? (bias + off3(obias, z)) : nullptr;
  if constexpr (QKV) {
    #pragma unroll
    for (int m = 0; m < MR; ++m) {
      const long long row0 = bm + wm * WM + m * 16 + g * 4;
      const int b = (int)(row0 >> 10), tt = (int)(row0 & 1023);
      #pragma unroll
      for (int n = 0; n < NR; ++n) {
        const int col = (int)(bn + wn * WN + n * 16 + l15);
        const float bv = bp[col];
        const int sec = col >> 9, d = col & 511;
        u16 vb[4];
        #pragma unroll
        for (int r = 0; r < 4; ++r) vb[r] = f2b(acc[m][n][r] + bv);
        if (sec == 0) {
          #pragma unroll
          for (int r = 0; r < 4; ++r)
            ((u16*)Cv)[(row0 + r) * 512 + d] = vb[r];
        } else {
          u16* dst = (sec == 1 ? kTo : vTo);
          ushort4 p4; p4.x = vb[0]; p4.y = vb[1]; p4.z = vb[2]; p4.w = vb[3];
          *(ushort4*)(dst + (size_t)(b * 8 + (d >> 6)) * 65536 + (size_t)(d & 63) * 1024 + tt) = p4;
        }
      }
    }
  } else {
    #pragma unroll
    for (int m = 0; m < MR; ++m) {
      const long long row0 = bm + wm * WM + m * 16 + g * 4;
      #pragma unroll
      for (int n = 0; n < NR; ++n) {
        const long long col = bn + wn * WN + n * 16 + l15;
        const float bv = bp ? bp[col] : 0.0f;
        #pragma unroll
        for (int r = 0; r < 4; ++r) {
          float v = acc[m][n][r] * alpha + bv;
          if (ACT == 1) v = fmaxf(v, 0.0f);
          const long long idx = cb + (row0 + r) * (long long)ldc + col;
          if constexpr (C_BF16) ((u16*)Cv)[idx] = f2b(v);
          else                  ((float*)Cv)[idx] = v;
        }
      }
    }
  }
}

// ---------- sum 4 split-K partials -> bf16 ----------
__global__ __launch_bounds__(256) void mt_combine_kernel(
    const float* __restrict__ part, u16* __restrict__ out)
{
  const int i = blockIdx.x * 256 + threadIdx.x;
  const float s = part[i] + part[i + 524288] + part[i + 2 * 524288] + part[i + 3 * 524288];
  out[i] = f2b(s);
}

// ---------- fused attention tail (v8 = v6 + bf16 partials + hoisted v + setprio) ----------
// 1D grid 1024: id = h8(3) | tb(4) | sp(1) | b(2). XCD pin via h8 = id&7.
// Block: 128 threads = 2 waves, each wave owns 32 t (t = tb*64 + wave*32 + l31).
// Phase 0: lat = relu(0.125*q@MT^T + be) via mfma32 (q, MT from L2), C-frag ->
//          B-frag via cvt_pk + shfl_xor(32).
// Loop: 16 chunks of 32 s; rec P^T = mfma32(wd_frag, latf); pe = exp(sigmoid(.+bd));
//       PV A-frag in-register; v B-frags direct from L2. Partials stored bf16.
__global__ __launch_bounds__(128, 2) void attn_tail_kernel(
    const u16* __restrict__ q, const u16* __restrict__ MT,
    const float* __restrict__ be, const u16* __restrict__ wdT,
    const float* __restrict__ bd, const u16* __restrict__ vT,
    u16* __restrict__ o_part, float* __restrict__ rs_part)
{
  __shared__ alignas(16) u16 wdL[2][32 * 256];   // 2 x 16 KB: [s:32][u:256]
  const int id = blockIdx.x;
  const int h8 = id & 7;
  const int tb = (id >> 3) & 15;
  const int sp = (id >> 7) & 1;
  const int b  = id >> 8;
  const int z  = b * 8 + h8;
  const int lane = threadIdx.x & 63, wave = threadIdx.x >> 6;  // wave 0..1
  const int l31 = lane & 31, h = lane >> 5;
  const int s0 = sp * 512;
  const u16* wdh  = wdT + (size_t)h8 * 262144;
  const float* bdh = bd + (size_t)h8 * 1024 + s0;
  const u16* vz = vT + (size_t)z * 65536 + s0;    // [d:64][s:1024] + s0

#define ASTAGE(buf, sc)                                                          \
  {                                                                              \
    const int sb_ = (sc) * 32;                                                   \
    _Pragma("unroll")                                                            \
    for (int j = 0; j < 8; ++j) {                                                \
      const int c = j * 128 + threadIdx.x;                                       \
      const int row = c >> 5, slot = c & 31;                                     \
      __builtin_amdgcn_global_load_lds(                                          \
          (gas_p)(wdh + (size_t)(s0 + sb_ + row) * 256 + ((slot ^ (row & 7)) << 3)), \
          (las_p)(&wdL[buf][c * 8]), 16, 0, 0);                                  \
    }                                                                            \
  }

  ASTAGE(0, 0);     // wd chunk 0 in flight while lat computes below

  // ---- phase 0: lat in registers ----
  // B-op (q): col t, k = d; A-op (MT): row u, k = d.
  short8 latf[16];
  {
    const int t = tb * 64 + wave * 32 + l31;
    const u16* qp = q + ((size_t)b * 1024 + t) * 512 + h8 * 64 + h * 8;
    const u16* mtp = MT + (size_t)z * 16384 + (size_t)l31 * 64 + h * 8;
    const float* beh = be + h8 * 256;
    short8 qf[4];
    #pragma unroll
    for (int kd = 0; kd < 4; ++kd) qf[kd] = *(const short8*)(qp + kd * 16);
    #pragma unroll
    for (int ublk = 0; ublk < 8; ++ublk) {
      f32x16 lacc = {};
      #pragma unroll
      for (int kd = 0; kd < 4; ++kd) {
        const short8 mtf = *(const short8*)(mtp + ublk * 2048 + kd * 16);
        lacc = __builtin_amdgcn_mfma_f32_32x32x16_bf16(mtf, qf[kd], lacc, 0, 0, 0);
      }
      float pe[16];
      #pragma unroll
      for (int q4 = 0; q4 < 4; ++q4) {
        const float4 b4 = *(const float4*)(beh + ublk * 32 + q4 * 8 + 4 * h);
        #pragma unroll
        for (int r2 = 0; r2 < 4; ++r2)
          pe[q4 * 4 + r2] = fmaxf(lacc[q4 * 4 + r2] * 0.125f + ((const float*)&b4)[r2], 0.0f);
      }
      unsigned w[8];
      #pragma unroll
      for (int i = 0; i < 8; ++i)
        asm("v_cvt_pk_bf16_f32 %0, %1, %2" : "=v"(w[i]) : "v"(pe[2 * i]), "v"(pe[2 * i + 1]));
      // kg even: u%32 in [0,16)
      {
        const unsigned sA = h ? w[0] : w[2];
        const unsigned rA = (unsigned)__shfl_xor((int)sA, 32);
        const unsigned sB = h ? w[1] : w[3];
        const unsigned rB = (unsigned)__shfl_xor((int)sB, 32);
        short8 f;
        ((unsigned*)&f)[0] = h ? rA : w[0];
        ((unsigned*)&f)[1] = h ? rB : w[1];
        ((unsigned*)&f)[2] = h ? w[2] : rA;
        ((unsigned*)&f)[3] = h ? w[3] : rB;
        latf[2 * ublk] = f;
      }
      // kg odd: u%32 in [16,32)
      {
        const unsigned sA = h ? w[4] : w[6];
        const unsigned rA = (unsigned)__shfl_xor((int)sA, 32);
        const unsigned sB = h ? w[5] : w[7];
        const unsigned rB = (unsigned)__shfl_xor((int)sB, 32);
        short8 f;
        ((unsigned*)&f)[0] = h ? rA : w[4];
        ((unsigned*)&f)[1] = h ? rB : w[5];
        ((unsigned*)&f)[2] = h ? w[6] : rA;
        ((unsigned*)&f)[3] = h ? w[7] : rB;
        latf[2 * ublk + 1] = f;
      }
    }
  }

  f32x16 oacc[2] = {};
  float rsum = 0.f;

  __syncthreads();   // wd chunk 0 staged
  int cur = 0;
  for (int sc = 0; sc < 16; ++sc) {
    if (sc < 15) ASTAGE(cur ^ 1, sc + 1);
    const int sb = sc * 32;

    // hoist v B-frags for both k2 halves (L2-resident; latency hides under rec)
    short8 vb[2][2];
    #pragma unroll
    for (int k2 = 0; k2 < 2; ++k2)
      #pragma unroll
      for (int nd = 0; nd < 2; ++nd)
        vb[k2][nd] = *(const short8*)(vz + (size_t)(nd * 32 + l31) * 1024 + sb + k2 * 16 + 8 * h);

    // rec: pacc = P^T frag (s' = (r&3)+8(r>>2)+4h, t = l31)
    f32x16 pacc = {};
    __builtin_amdgcn_s_setprio(1);
    #pragma unroll
    for (int kg = 0; kg < 16; ++kg) {
      const short8 a = *(const short8*)(&wdL[cur][l31 * 256 + (((kg * 2 + h) ^ (l31 & 7)) << 3)]);
      pacc = __builtin_amdgcn_mfma_f32_32x32x16_bf16(a, latf[kg], pacc, 0, 0, 0);
    }
    __builtin_amdgcn_s_setprio(0);

    // per 16-s half: epilogue + in-register P rebuild + PV (v from L2)
    #pragma unroll
    for (int k2 = 0; k2 < 2; ++k2) {
      float pe[8];
      #pragma unroll
      for (int p4 = 0; p4 < 2; ++p4) {
        const int pp = k2 * 2 + p4;
        const float4 b4 = *(const float4*)(bdh + sb + pp * 8 + 4 * h);
        #pragma unroll
        for (int qq = 0; qq < 4; ++qq) {
          const float val = pacc[pp * 4 + qq] + ((const float*)&b4)[qq];
          const float sig = 1.0f / (1.0f + __expf(-val));
          pe[p4 * 4 + qq] = __expf(sig);
          rsum += pe[p4 * 4 + qq];
        }
      }
      unsigned wloA, wloB, whiA, whiB;
      asm("v_cvt_pk_bf16_f32 %0, %1, %2" : "=v"(wloA) : "v"(pe[0]), "v"(pe[1]));
      asm("v_cvt_pk_bf16_f32 %0, %1, %2" : "=v"(wloB) : "v"(pe[2]), "v"(pe[3]));
      asm("v_cvt_pk_bf16_f32 %0, %1, %2" : "=v"(whiA) : "v"(pe[4]), "v"(pe[5]));
      asm("v_cvt_pk_bf16_f32 %0, %1, %2" : "=v"(whiB) : "v"(pe[6]), "v"(pe[7]));
      const unsigned xA = h ? wloA : whiA;
      const unsigned rA = (unsigned)__shfl_xor((int)xA, 32);
      const unsigned xB = h ? wloB : whiB;
      const unsigned rB = (unsigned)__shfl_xor((int)xB, 32);
      short8 pa;
      ((unsigned*)&pa)[0] = h ? rA : wloA;
      ((unsigned*)&pa)[1] = h ? rB : wloB;
      ((unsigned*)&pa)[2] = h ? whiA : rA;
      ((unsigned*)&pa)[3] = h ? whiB : rB;
      __builtin_amdgcn_s_setprio(1);
      #pragma unroll
      for (int nd = 0; nd < 2; ++nd)
        oacc[nd] = __builtin_amdgcn_mfma_f32_32x32x16_bf16(pa, vb[k2][nd], oacc[nd], 0, 0, 0);
      __builtin_amdgcn_s_setprio(0);
    }
    __syncthreads();
    cur ^= 1;
  }
#undef ASTAGE

  rsum += __shfl_xor(rsum, 32);
  const long long orow0 = (long long)b * 1024 + tb * 64 + wave * 32;
  u16* op = o_part + (size_t)sp * ((size_t)BT * EE);
  #pragma unroll
  for (int nd = 0; nd < 2; ++nd)
    #pragma unroll
    for (int r = 0; r < 16; ++r) {
      const int trow = (r & 3) + 8 * (r >> 2) + 4 * h;
      op[(orow0 + trow) * 512 + h8 * 64 + nd * 32 + l31] = f2b(oacc[nd][r]);
    }
  if (h == 0)
    rs_part[(size_t)sp * 32768 + (size_t)z * 1024 + tb * 64 + wave * 32 + l31] = rsum;
}

// ---------- combine partials: o = (Σ o_p) / (Σ rs_p), bf16 ----------
__global__ __launch_bounds__(256) void attn_combine_kernel(
    const u16* __restrict__ o_part, const float* __restrict__ rs_part,
    u16* __restrict__ o)
{
  const int row = blockIdx.x;
  const int b = row >> 10, t = row & 1023;
  #pragma unroll
  for (int j = 0; j < 2; ++j) {
    const int c = j * 256 + threadIdx.x;
    const int bh = b * 8 + (c >> 6);
    float rs = 0.f, v = 0.f;
    #pragma unroll
    for (int p = 0; p < 2; ++p) {
      rs += rs_part[(size_t)p * 32768 + (size_t)bh * 1024 + t];
      v  += b2f(o_part[(size_t)p * BT * EE + (size_t)row * 512 + c]);
    }
    o[(size_t)row * 512 + c] = f2b(v / rs);
  }
}

// ---------- embedding ----------
__global__ __launch_bounds__(256) void embed_kernel(
    const float* __restrict__ tok, const float* __restrict__ pos,
    const int* __restrict__ x, float* __restrict__ h, u16* __restrict__ hb)
{
  const long long row = blockIdx.x;
  const int t = (int)(row & (TT - 1));
  const long long tokid = x[row];
  const float* te = tok + tokid * EE;
  const float* pe = pos + (long long)t * EE;
  const long long base = row * EE;
  for (int e = threadIdx.x; e < EE; e += 256) {
    float v = te[e] + pe[e];
    h[base + e] = v;
    hb[base + e] = f2b(v);
  }
}

// ---------- residual + layernorm (bf16 delta) ----------
__global__ __launch_bounds__(256) void addnorm_kernel(
    const float* __restrict__ hin, const u16* __restrict__ delta,
    const float* __restrict__ g, const float* __restrict__ bta,
    float* __restrict__ hout, u16* __restrict__ hbout)
{
  __shared__ float sm[8];
  const long long base = (long long)blockIdx.x * EE;
  const int tid = threadIdx.x;
  float x0 = hin[base + tid] + b2f(delta[base + tid]);
  float x1 = hin[base + tid + 256] + b2f(delta[base + tid + 256]);
  float s = x0 + x1, ss = x0 * x0 + x1 * x1;
  #pragma unroll
  for (int o = 32; o; o >>= 1) { s += __shfl_down(s, o); ss += __shfl_down(ss, o); }
  if ((tid & 63) == 0) { sm[tid >> 6] = s; sm[4 + (tid >> 6)] = ss; }
  __syncthreads();
  const float S = sm[0] + sm[1] + sm[2] + sm[3];
  const float SS = sm[4] + sm[5] + sm[6] + sm[7];
  const float mu = S * (1.0f / EE);
  const float var = SS * (1.0f / EE) - mu * mu;
  const float inv = rsqrtf(var + 1e-5f);
  const float y0 = (x0 - mu) * inv * g[tid] + bta[tid];
  const float y1 = (x1 - mu) * inv * g[tid + 256] + bta[tid + 256];
  hout[base + tid] = y0;       hout[base + tid + 256] = y1;
  hbout[base + tid] = f2b(y0); hbout[base + tid + 256] = f2b(y1);
}

// ---------- LDS-tiled transpose-convert ----------
template<typename ST>
__global__ __launch_bounds__(256) void transposeT_kernel(
    u16* __restrict__ dst, const ST* __restrict__ src,
    int ldsrc, int lddst, Off3 dstz, Off3 srcz)
{
  __shared__ float t[32][33];
  const int z = blockIdx.z;
  const ST* s = src + off3(srcz, z);
  u16* d = dst + off3(dstz, z);
  const int r0 = blockIdx.x * 32, c0 = blockIdx.y * 32;
  const int tx = threadIdx.x & 31, ty = threadIdx.x >> 5;
  #pragma unroll
  for (int j = 0; j < 4; ++j) {
    const int r = ty + j * 8;
    t[r][tx] = tof(s[(long long)(r0 + r) * ldsrc + c0 + tx]);
  }
  __syncthreads();
  #pragma unroll
  for (int j = 0; j < 4; ++j) {
    const int c = ty + j * 8;
    d[(long long)(c0 + c) * lddst + r0 + tx] = f2b(t[tx][c]);
  }
}

// ---------- stack bq|bk|bv per layer ----------
__global__ __launch_bounds__(256) void biaspack_kernel(
    float* __restrict__ dst, const float* __restrict__ bq,
    const float* __restrict__ bk, const float* __restrict__ bv)
{
  const int i = blockIdx.x * 256 + threadIdx.x;
  if (i >= LL * 1536) return;
  const int l = i / 1536, j = i % 1536;
  dst[i] = (j < 512) ? bq[l * 512 + j]
         : (j < 1024) ? bk[l * 512 + j - 512]
                      : bv[l * 512 + j - 1024];
}

__global__ void finalize_loss(float* out) { out[0] = LAMBDA * (float)(LL * 32 * 1024); }

// ---------- host ----------
extern "C" void kernel_launch(void* const* d_in, const int* in_sizes, int n_in,
                              void* d_out, int out_size, void* d_ws, size_t ws_size,
                              hipStream_t stream)
{
  (void)in_sizes; (void)n_in; (void)out_size; (void)ws_size;
  const float* tok = (const float*)d_in[0];
  const float* pos = (const float*)d_in[1];
  const float* wq  = (const float*)d_in[2];
  const float* bq  = (const float*)d_in[3];
  const float* wk  = (const float*)d_in[4];
  const float* bk  = (const float*)d_in[5];
  const float* wv  = (const float*)d_in[6];
  const float* bv  = (const float*)d_in[7];
  const float* we  = (const float*)d_in[8];
  const float* be  = (const float*)d_in[9];
  const float* wd  = (const float*)d_in[10];
  const float* bd  = (const float*)d_in[11];
  const float* wo  = (const float*)d_in[12];
  const float* bo  = (const float*)d_in[13];
  const float* ln1g = (const float*)d_in[14];
  const float* ln1b = (const float*)d_in[15];
  const float* w1  = (const float*)d_in[16];
  const float* b1  = (const float*)d_in[17];
  const float* w2  = (const float*)d_in[18];
  const float* b2  = (const float*)d_in[19];
  const float* ln2g = (const float*)d_in[20];
  const float* ln2b = (const float*)d_in[21];
  const int*   x   = (const int*)d_in[22];

  char* ws = (char*)d_ws;
  size_t off = 0;
  auto alloc = [&](size_t bytes) { void* p = ws + off; off = (off + bytes + 255) & ~255ULL; return p; };

  u16*  wqkvT = (u16*)alloc((size_t)LL * 3 * 512 * 512 * 2);
  u16*  weT   = (u16*)alloc((size_t)LL * HH * T4 * TT * 2);
  u16*  wdT   = (u16*)alloc((size_t)LL * HH * TT * T4 * 2);
  u16*  woT   = (u16*)alloc((size_t)LL * EE * EE * 2);
  u16*  w1T   = (u16*)alloc((size_t)LL * FF * EE * 2);
  u16*  w2T   = (u16*)alloc((size_t)LL * EE * FF * 2);
  float* bqkv = (float*)alloc((size_t)LL * 1536 * 4);
  float* h_f  = (float*)alloc((size_t)BT * EE * 4);
  u16*  h_b   = (u16*)alloc((size_t)BT * EE * 2);
  u16*  q_b   = (u16*)alloc((size_t)BT * EE * 2);
  u16*  kT_b  = (u16*)alloc((size_t)32 * HD * TT * 2);
  u16*  vT_b  = (u16*)alloc((size_t)32 * HD * TT * 2);
  u16*  MT_b  = (u16*)alloc((size_t)32 * T4 * HD * 2);
  float* MT_part = (float*)alloc((size_t)4 * 32 * T4 * HD * 4);
  u16*  o_b   = (u16*)alloc((size_t)BT * EE * 2);
  u16*  attn_d = (u16*)alloc((size_t)BT * EE * 2);
  u16*  ff2_d  = (u16*)alloc((size_t)BT * EE * 2);
  u16*  ff1_b = (u16*)alloc((size_t)BT * FF * 2);
  u16*  o_part = (u16*)alloc((size_t)2 * BT * EE * 2);
  float* rs_part = (float*)alloc((size_t)2 * 32 * 1024 * 4);

  const Off3 Z1 = {0, 0, 1};

  embed_kernel<<<dim3(BT), 256, 0, stream>>>(tok, pos, x, h_f, h_b);
  biaspack_kernel<<<dim3((LL * 1536 + 255) / 256), 256, 0, stream>>>(bqkv, bq, bk, bv);

  transposeT_kernel<float><<<dim3(16, 2, 48), 256, 0, stream>>>(
      wqkvT,          wq, 64, 512, Off3{786432, 32768, 8}, Off3{32768, 0, 1});
  transposeT_kernel<float><<<dim3(16, 2, 48), 256, 0, stream>>>(
      wqkvT + 262144, wk, 64, 512, Off3{786432, 32768, 8}, Off3{32768, 0, 1});
  transposeT_kernel<float><<<dim3(16, 2, 48), 256, 0, stream>>>(
      wqkvT + 524288, wv, 64, 512, Off3{786432, 32768, 8}, Off3{32768, 0, 1});
  transposeT_kernel<float><<<dim3(32, 8, 48), 256, 0, stream>>>(
      weT, we, 256, 1024, Off3{262144, 0, 1}, Off3{262144, 0, 1});
  transposeT_kernel<float><<<dim3(8, 32, 48), 256, 0, stream>>>(
      wdT, wd, 1024, 256, Off3{262144, 0, 1}, Off3{262144, 0, 1});
  transposeT_kernel<float><<<dim3(16, 16, 6), 256, 0, stream>>>(
      woT, wo, 512, 512, Off3{262144, 0, 1}, Off3{262144, 0, 1});
  transposeT_kernel<float><<<dim3(16, 64, 6), 256, 0, stream>>>(
      w1T, w1, 2048, 512, Off3{1048576, 0, 1}, Off3{1048576, 0, 1});
  transposeT_kernel<float><<<dim3(64, 16, 6), 256, 0, stream>>>(
      w2T, w2, 512, 2048, Off3{1048576, 0, 1}, Off3{1048576, 0, 1});

  for (int l = 0; l < LL; ++l) {
    // --- fused q|k|v projection; q row-major, k/v transposed per head ---
    gemm_p<64, 128, true, 0, false, true><<<dim3(64, 12, 1), 256, 0, stream>>>(
        h_b, wqkvT + (size_t)l * 786432, q_b, bqkv + l * 1536, 1.0f,
        512, 512, 512, 512, Z1, Z1, Z1, Z1, 0, kT_b, vT_b);

    // --- MT[u][d] = sum_s we[s][u] k[s][d] : split-K x4 ---
    gemm_p<64, 64, false, 0, true, false><<<dim3(4, 4, 32), 256, 0, stream>>>(
        weT + (size_t)l * 2097152, kT_b, MT_part, nullptr, 1.0f,
        256, 1024, 1024, 64,
        Off3{0, 262144, 8}, Off3{65536, 0, 1}, Off3{16384, 0, 1}, Z1, 524288,
        nullptr, nullptr);
    mt_combine_kernel<<<dim3(2048), 256, 0, stream>>>(MT_part, MT_b);

    // --- fused tail: lat in-register; P = exp(sigmoid(lat@wd+bd)); bf16 partials ---
    attn_tail_kernel<<<dim3(1024), 128, 0, stream>>>(
        q_b, MT_b, be + (size_t)l * 2048, wdT + (size_t)l * 2097152,
        bd + (size_t)l * 8192, vT_b, o_part, rs_part);
    attn_combine_kernel<<<dim3(BT), 256, 0, stream>>>(o_part, rs_part, o_b);

    // --- attn out projection ---
    gemm_p<64, 64, true, 0, false, false><<<dim3(64, 8, 1), 256, 0, stream>>>(
        o_b, woT + (size_t)l * 262144, attn_d, bo + l * 512, 1.0f,
        512, 512, 512, 512, Z1, Z1, Z1, Z1, 0, nullptr, nullptr);

    addnorm_kernel<<<dim3(BT), 256, 0, stream>>>(h_f, attn_d, ln1g + l * 512, ln1b + l * 512, h_f, h_b);

    // --- FFN ---
    gemm_p<64, 128, true, 1, false, false><<<dim3(64, 16, 1), 256, 0, stream>>>(
        h_b, w1T + (size_t)l * 1048576, ff1_b, b1 + l * 2048, 1.0f,
        512, 512, 512, 2048, Z1, Z1, Z1, Z1, 0, nullptr, nullptr);
    gemm_p<64, 64, true, 1, false, false><<<dim3(64, 8, 1), 256, 0, stream>>>(
        ff1_b, w2T + (size_t)l * 1048576, ff2_d, b2 + l * 512, 1.0f,
        2048, 2048, 2048, 512, Z1, Z1, Z1, Z1, 0, nullptr, nullptr);

    float* hout = (l == LL - 1) ? (float*)d_out : h_f;
    addnorm_kernel<<<dim3(BT), 256, 0, stream>>>(h_f, ff2_d, ln2g + l * 512, ln2b + l * 512, hout, h_b);
  }

  finalize_loss<<<1, 1, 0, stream>>>((float*)d_out + (size_t)BT * EE);
}

// Round 17
// 933.221 us; speedup vs baseline: 1.1389x; 1.0633x over previous
//
#include <hip/hip_runtime.h>

typedef unsigned short u16;
typedef __attribute__((ext_vector_type(8))) short short8;
typedef __attribute__((ext_vector_type(4))) float f32x4;
typedef __attribute__((ext_vector_type(16))) float f32x16;
typedef const __attribute__((address_space(1))) void* gas_p;
typedef __attribute__((address_space(3))) void* las_p;

// ---------- constants ----------
#define LL (6)
#define BB (4)
#define TT (1024)
#define EE (512)
#define HH (8)
#define HD (64)
#define T4 (256)
#define FF (2048)
#define BT (BB*TT)           // 4096
#define LAMBDA (0.001f)

// ---------- helpers ----------
struct Off3 { long long hi, lo; int mod; };
__device__ __forceinline__ long long off3(Off3 o, int z) {
  return (long long)(z / o.mod) * o.hi + (long long)(z % o.mod) * o.lo;
}
__device__ __forceinline__ float b2f(u16 u) { return __uint_as_float((unsigned)u << 16); }
__device__ __forceinline__ u16 f2b(float f) {
  unsigned u = __float_as_uint(f);
  return (u16)((u + 0x7fffu + ((u >> 16) & 1u)) >> 16);   // RNE
}
__device__ __forceinline__ float tof(float v) { return v; }
__device__ __forceinline__ float tof(u16 v) { return b2f(v); }

// ---------- pipelined MFMA GEMM: C = act(alpha * A @ Bt^T + bias) ----------
// BK=64, double-buffered LDS; stage(next) before compute(cur); 1 barrier/K-step.
// QKV mode: N=1536 cols = q|k|v; q row-major, k/v transposed per head.
template<int BM, int BN, bool C_BF16, int ACT, bool SPLITK, bool QKV>
__global__ __launch_bounds__(256) void gemm_p(
    const u16* __restrict__ A, const u16* __restrict__ Bt, void* __restrict__ Cv,
    const float* __restrict__ bias, float alpha,
    int K, int lda, int ldb, int ldc,
    Off3 oa, Off3 ob, Off3 oc, Off3 obias, long long sstride,
    u16* __restrict__ kTo, u16* __restrict__ vTo)
{
  constexpr int BK = 64;
  constexpr int WM = BM / 2, WN = BN / 2;
  constexpr int MR = WM / 16, NR = WN / 16;
  __shared__ alignas(16) u16 lA[2][BM * BK];
  __shared__ alignas(16) u16 lB[2][BN * BK];

  const int z = blockIdx.z;
  A  += off3(oa, z);
  Bt += off3(ob, z);
  long long cb = off3(oc, z);
  long long bn;
  if constexpr (SPLITK) {
    const long long kb = (long long)blockIdx.y * K;
    A += kb; Bt += kb;
    cb += (long long)blockIdx.y * sstride;
    bn = 0;
  } else {
    bn = (long long)blockIdx.y * BN;
  }
  const int tid = threadIdx.x;
  const int lane = tid & 63, wave = tid >> 6;
  const int wm = wave >> 1, wn = wave & 1;
  const int l15 = lane & 15, g = lane >> 4;
  const long long bm = (long long)blockIdx.x * BM;

#define STAGE(buf, k0)                                                          \
  {                                                                             \
    _Pragma("unroll")                                                           \
    for (int j = 0; j < (BM * 8) / 256; ++j) {                                  \
      const int c = j * 256 + tid, row = c >> 3, slot = c & 7;                  \
      const u16* src = A + (bm + row) * (long long)lda + (k0) +                 \
                       ((slot ^ (row & 7)) << 3);                               \
      __builtin_amdgcn_global_load_lds((gas_p)src, (las_p)(&lA[buf][c * 8]), 16, 0, 0); \
    }                                                                           \
    _Pragma("unroll")                                                           \
    for (int j = 0; j < (BN * 8) / 256; ++j) {                                  \
      const int c = j * 256 + tid, row = c >> 3, slot = c & 7;                  \
      const u16* src = Bt + (bn + row) * (long long)ldb + (k0) +                \
                       ((slot ^ (row & 7)) << 3);                               \
      __builtin_amdgcn_global_load_lds((gas_p)src, (las_p)(&lB[buf][c * 8]), 16, 0, 0); \
    }                                                                           \
  }

  f32x4 acc[MR][NR] = {};
  STAGE(0, 0);
  __syncthreads();
  int cur = 0;
  for (int k0 = 0; k0 < K; k0 += BK) {
    if (k0 + BK < K) STAGE(cur ^ 1, k0 + BK);
    #pragma unroll
    for (int kk = 0; kk < 2; ++kk) {
      short8 af[MR], bfr[NR];
      #pragma unroll
      for (int m = 0; m < MR; ++m) {
        const int row = wm * WM + m * 16 + l15;
        af[m] = *(const short8*)(&lA[cur][row * BK + ((((kk << 2) + g) ^ (row & 7)) << 3)]);
      }
      #pragma unroll
      for (int n = 0; n < NR; ++n) {
        const int row = wn * WN + n * 16 + l15;
        bfr[n] = *(const short8*)(&lB[cur][row * BK + ((((kk << 2) + g) ^ (row & 7)) << 3)]);
      }
      #pragma unroll
      for (int m = 0; m < MR; ++m)
        #pragma unroll
        for (int n = 0; n < NR; ++n)
          acc[m][n] = __builtin_amdgcn_mfma_f32_16x16x32_bf16(af[m], bfr[n], acc[m][n], 0, 0, 0);
    }
    __syncthreads();
    cur ^= 1;
  }
#undef STAGE

  const float* bp = bias ? (bias + off3(obias, z)) : nullptr;
  if constexpr (QKV) {
    #pragma unroll
    for (int m = 0; m < MR; ++m) {
      const long long row0 = bm + wm * WM + m * 16 + g * 4;
      const int b = (int)(row0 >> 10), tt = (int)(row0 & 1023);
      #pragma unroll
      for (int n = 0; n < NR; ++n) {
        const int col = (int)(bn + wn * WN + n * 16 + l15);
        const float bv = bp[col];
        const int sec = col >> 9, d = col & 511;
        u16 vb[4];
        #pragma unroll
        for (int r = 0; r < 4; ++r) vb[r] = f2b(acc[m][n][r] + bv);
        if (sec == 0) {
          #pragma unroll
          for (int r = 0; r < 4; ++r)
            ((u16*)Cv)[(row0 + r) * 512 + d] = vb[r];
        } else {
          u16* dst = (sec == 1 ? kTo : vTo);
          ushort4 p4; p4.x = vb[0]; p4.y = vb[1]; p4.z = vb[2]; p4.w = vb[3];
          *(ushort4*)(dst + (size_t)(b * 8 + (d >> 6)) * 65536 + (size_t)(d & 63) * 1024 + tt) = p4;
        }
      }
    }
  } else {
    #pragma unroll
    for (int m = 0; m < MR; ++m) {
      const long long row0 = bm + wm * WM + m * 16 + g * 4;
      #pragma unroll
      for (int n = 0; n < NR; ++n) {
        const long long col = bn + wn * WN + n * 16 + l15;
        const float bv = bp ? bp[col] : 0.0f;
        #pragma unroll
        for (int r = 0; r < 4; ++r) {
          float v = acc[m][n][r] * alpha + bv;
          if (ACT == 1) v = fmaxf(v, 0.0f);
          const long long idx = cb + (row0 + r) * (long long)ldc + col;
          if constexpr (C_BF16) ((u16*)Cv)[idx] = f2b(v);
          else                  ((float*)Cv)[idx] = v;
        }
      }
    }
  }
}

// ---------- sum 4 split-K partials -> bf16 ----------
__global__ __launch_bounds__(256) void mt_combine_kernel(
    const float* __restrict__ part, u16* __restrict__ out)
{
  const int i = blockIdx.x * 256 + threadIdx.x;
  const float s = part[i] + part[i + 524288] + part[i + 2 * 524288] + part[i + 3 * 524288];
  out[i] = f2b(s);
}

// ---------- fused attention tail (v9 = v8 + split pacc ILP + rcp sigmoid) ----------
// 1D grid 1024: id = h8(3) | tb(4) | sp(1) | b(2). XCD pin via h8 = id&7.
// Block: 128 threads = 2 waves, each wave owns 32 t (t = tb*64 + wave*32 + l31).
// Phase 0: lat = relu(0.125*q@MT^T + be) via mfma32 (q, MT from L2), C-frag ->
//          B-frag via cvt_pk + shfl_xor(32).
// Loop: 16 chunks of 32 s; rec P^T = mfma32(wd_frag, latf) with TWO independent
//       accumulators (chain depth 16 -> 8); pe = exp(sigmoid(.+bd)) with v_rcp;
//       PV A-frag in-register; v B-frags direct from L2. Partials stored bf16.
__global__ __launch_bounds__(128, 2) void attn_tail_kernel(
    const u16* __restrict__ q, const u16* __restrict__ MT,
    const float* __restrict__ be, const u16* __restrict__ wdT,
    const float* __restrict__ bd, const u16* __restrict__ vT,
    u16* __restrict__ o_part, float* __restrict__ rs_part)
{
  __shared__ alignas(16) u16 wdL[2][32 * 256];   // 2 x 16 KB: [s:32][u:256]
  const int id = blockIdx.x;
  const int h8 = id & 7;
  const int tb = (id >> 3) & 15;
  const int sp = (id >> 7) & 1;
  const int b  = id >> 8;
  const int z  = b * 8 + h8;
  const int lane = threadIdx.x & 63, wave = threadIdx.x >> 6;  // wave 0..1
  const int l31 = lane & 31, h = lane >> 5;
  const int s0 = sp * 512;
  const u16* wdh  = wdT + (size_t)h8 * 262144;
  const float* bdh = bd + (size_t)h8 * 1024 + s0;
  const u16* vz = vT + (size_t)z * 65536 + s0;    // [d:64][s:1024] + s0

#define ASTAGE(buf, sc)                                                          \
  {                                                                              \
    const int sb_ = (sc) * 32;                                                   \
    _Pragma("unroll")                                                            \
    for (int j = 0; j < 8; ++j) {                                                \
      const int c = j * 128 + threadIdx.x;                                       \
      const int row = c >> 5, slot = c & 31;                                     \
      __builtin_amdgcn_global_load_lds(                                          \
          (gas_p)(wdh + (size_t)(s0 + sb_ + row) * 256 + ((slot ^ (row & 7)) << 3)), \
          (las_p)(&wdL[buf][c * 8]), 16, 0, 0);                                  \
    }                                                                            \
  }

  ASTAGE(0, 0);     // wd chunk 0 in flight while lat computes below

  // ---- phase 0: lat in registers ----
  // B-op (q): col t, k = d; A-op (MT): row u, k = d.
  short8 latf[16];
  {
    const int t = tb * 64 + wave * 32 + l31;
    const u16* qp = q + ((size_t)b * 1024 + t) * 512 + h8 * 64 + h * 8;
    const u16* mtp = MT + (size_t)z * 16384 + (size_t)l31 * 64 + h * 8;
    const float* beh = be + h8 * 256;
    short8 qf[4];
    #pragma unroll
    for (int kd = 0; kd < 4; ++kd) qf[kd] = *(const short8*)(qp + kd * 16);
    #pragma unroll
    for (int ublk = 0; ublk < 8; ++ublk) {
      f32x16 lacc = {};
      #pragma unroll
      for (int kd = 0; kd < 4; ++kd) {
        const short8 mtf = *(const short8*)(mtp + ublk * 2048 + kd * 16);
        lacc = __builtin_amdgcn_mfma_f32_32x32x16_bf16(mtf, qf[kd], lacc, 0, 0, 0);
      }
      float pe[16];
      #pragma unroll
      for (int q4 = 0; q4 < 4; ++q4) {
        const float4 b4 = *(const float4*)(beh + ublk * 32 + q4 * 8 + 4 * h);
        #pragma unroll
        for (int r2 = 0; r2 < 4; ++r2)
          pe[q4 * 4 + r2] = fmaxf(lacc[q4 * 4 + r2] * 0.125f + ((const float*)&b4)[r2], 0.0f);
      }
      unsigned w[8];
      #pragma unroll
      for (int i = 0; i < 8; ++i)
        asm("v_cvt_pk_bf16_f32 %0, %1, %2" : "=v"(w[i]) : "v"(pe[2 * i]), "v"(pe[2 * i + 1]));
      // kg even: u%32 in [0,16)
      {
        const unsigned sA = h ? w[0] : w[2];
        const unsigned rA = (unsigned)__shfl_xor((int)sA, 32);
        const unsigned sB = h ? w[1] : w[3];
        const unsigned rB = (unsigned)__shfl_xor((int)sB, 32);
        short8 f;
        ((unsigned*)&f)[0] = h ? rA : w[0];
        ((unsigned*)&f)[1] = h ? rB : w[1];
        ((unsigned*)&f)[2] = h ? w[2] : rA;
        ((unsigned*)&f)[3] = h ? w[3] : rB;
        latf[2 * ublk] = f;
      }
      // kg odd: u%32 in [16,32)
      {
        const unsigned sA = h ? w[4] : w[6];
        const unsigned rA = (unsigned)__shfl_xor((int)sA, 32);
        const unsigned sB = h ? w[5] : w[7];
        const unsigned rB = (unsigned)__shfl_xor((int)sB, 32);
        short8 f;
        ((unsigned*)&f)[0] = h ? rA : w[4];
        ((unsigned*)&f)[1] = h ? rB : w[5];
        ((unsigned*)&f)[2] = h ? w[6] : rA;
        ((unsigned*)&f)[3] = h ? w[7] : rB;
        latf[2 * ublk + 1] = f;
      }
    }
  }

  f32x16 oacc[2] = {};
  float rsum = 0.f;

  __syncthreads();   // wd chunk 0 staged
  int cur = 0;
  for (int sc = 0; sc < 16; ++sc) {
    if (sc < 15) ASTAGE(cur ^ 1, sc + 1);
    const int sb = sc * 32;

    // hoist v B-frags for both k2 halves (L2-resident; latency hides under rec)
    short8 vb[2][2];
    #pragma unroll
    for (int k2 = 0; k2 < 2; ++k2)
      #pragma unroll
      for (int nd = 0; nd < 2; ++nd)
        vb[k2][nd] = *(const short8*)(vz + (size_t)(nd * 32 + l31) * 1024 + sb + k2 * 16 + 8 * h);

    // rec: two independent accumulator chains (kg even / odd) -> 2x MFMA ILP
    f32x16 pacc0 = {}, pacc1 = {};
    __builtin_amdgcn_s_setprio(1);
    #pragma unroll
    for (int kg = 0; kg < 16; kg += 2) {
      const short8 a0 = *(const short8*)(&wdL[cur][l31 * 256 + ((((kg + 0) * 2 + h) ^ (l31 & 7)) << 3)]);
      pacc0 = __builtin_amdgcn_mfma_f32_32x32x16_bf16(a0, latf[kg + 0], pacc0, 0, 0, 0);
      const short8 a1 = *(const short8*)(&wdL[cur][l31 * 256 + ((((kg + 1) * 2 + h) ^ (l31 & 7)) << 3)]);
      pacc1 = __builtin_amdgcn_mfma_f32_32x32x16_bf16(a1, latf[kg + 1], pacc1, 0, 0, 0);
    }
    __builtin_amdgcn_s_setprio(0);

    // per 16-s half: epilogue + in-register P rebuild + PV (v from L2)
    #pragma unroll
    for (int k2 = 0; k2 < 2; ++k2) {
      float pe[8];
      #pragma unroll
      for (int p4 = 0; p4 < 2; ++p4) {
        const int pp = k2 * 2 + p4;
        const float4 b4 = *(const float4*)(bdh + sb + pp * 8 + 4 * h);
        #pragma unroll
        for (int qq = 0; qq < 4; ++qq) {
          const float val = pacc0[pp * 4 + qq] + pacc1[pp * 4 + qq] + ((const float*)&b4)[qq];
          const float sig = __builtin_amdgcn_rcpf(1.0f + __expf(-val));
          pe[p4 * 4 + qq] = __expf(sig);
          rsum += pe[p4 * 4 + qq];
        }
      }
      unsigned wloA, wloB, whiA, whiB;
      asm("v_cvt_pk_bf16_f32 %0, %1, %2" : "=v"(wloA) : "v"(pe[0]), "v"(pe[1]));
      asm("v_cvt_pk_bf16_f32 %0, %1, %2" : "=v"(wloB) : "v"(pe[2]), "v"(pe[3]));
      asm("v_cvt_pk_bf16_f32 %0, %1, %2" : "=v"(whiA) : "v"(pe[4]), "v"(pe[5]));
      asm("v_cvt_pk_bf16_f32 %0, %1, %2" : "=v"(whiB) : "v"(pe[6]), "v"(pe[7]));
      const unsigned xA = h ? wloA : whiA;
      const unsigned rA = (unsigned)__shfl_xor((int)xA, 32);
      const unsigned xB = h ? wloB : whiB;
      const unsigned rB = (unsigned)__shfl_xor((int)xB, 32);
      short8 pa;
      ((unsigned*)&pa)[0] = h ? rA : wloA;
      ((unsigned*)&pa)[1] = h ? rB : wloB;
      ((unsigned*)&pa)[2] = h ? whiA : rA;
      ((unsigned*)&pa)[3] = h ? whiB : rB;
      __builtin_amdgcn_s_setprio(1);
      #pragma unroll
      for (int nd = 0; nd < 2; ++nd)
        oacc[nd] = __builtin_amdgcn_mfma_f32_32x32x16_bf16(pa, vb[k2][nd], oacc[nd], 0, 0, 0);
      __builtin_amdgcn_s_setprio(0);
    }
    __syncthreads();
    cur ^= 1;
  }
#undef ASTAGE

  rsum += __shfl_xor(rsum, 32);
  const long long orow0 = (long long)b * 1024 + tb * 64 + wave * 32;
  u16* op = o_part + (size_t)sp * ((size_t)BT * EE);
  #pragma unroll
  for (int nd = 0; nd < 2; ++nd)
    #pragma unroll
    for (int r = 0; r < 16; ++r) {
      const int trow = (r & 3) + 8 * (r >> 2) + 4 * h;
      op[(orow0 + trow) * 512 + h8 * 64 + nd * 32 + l31] = f2b(oacc[nd][r]);
    }
  if (h == 0)
    rs_part[(size_t)sp * 32768 + (size_t)z * 1024 + tb * 64 + wave * 32 + l31] = rsum;
}

// ---------- combine partials: o = (Σ o_p) / (Σ rs_p), bf16 ----------
__global__ __launch_bounds__(256) void attn_combine_kernel(
    const u16* __restrict__ o_part, const float* __restrict__ rs_part,
    u16* __restrict__ o)
{
  const int row = blockIdx.x;
  const int b = row >> 10, t = row & 1023;
  #pragma unroll
  for (int j = 0; j < 2; ++j) {
    const int c = j * 256 + threadIdx.x;
    const int bh = b * 8 + (c >> 6);
    float rs = 0.f, v = 0.f;
    #pragma unroll
    for (int p = 0; p < 2; ++p) {
      rs += rs_part[(size_t)p * 32768 + (size_t)bh * 1024 + t];
      v  += b2f(o_part[(size_t)p * BT * EE + (size_t)row * 512 + c]);
    }
    o[(size_t)row * 512 + c] = f2b(v / rs);
  }
}

// ---------- embedding ----------
__global__ __launch_bounds__(256) void embed_kernel(
    const float* __restrict__ tok, const float* __restrict__ pos,
    const int* __restrict__ x, float* __restrict__ h, u16* __restrict__ hb)
{
  const long long row = blockIdx.x;
  const int t = (int)(row & (TT - 1));
  const long long tokid = x[row];
  const float* te = tok + tokid * EE;
  const float* pe = pos + (long long)t * EE;
  const long long base = row * EE;
  for (int e = threadIdx.x; e < EE; e += 256) {
    float v = te[e] + pe[e];
    h[base + e] = v;
    hb[base + e] = f2b(v);
  }
}

// ---------- residual + layernorm (bf16 delta) ----------
__global__ __launch_bounds__(256) void addnorm_kernel(
    const float* __restrict__ hin, const u16* __restrict__ delta,
    const float* __restrict__ g, const float* __restrict__ bta,
    float* __restrict__ hout, u16* __restrict__ hbout)
{
  __shared__ float sm[8];
  const long long base = (long long)blockIdx.x * EE;
  const int tid = threadIdx.x;
  float x0 = hin[base + tid] + b2f(delta[base + tid]);
  float x1 = hin[base + tid + 256] + b2f(delta[base + tid + 256]);
  float s = x0 + x1, ss = x0 * x0 + x1 * x1;
  #pragma unroll
  for (int o = 32; o; o >>= 1) { s += __shfl_down(s, o); ss += __shfl_down(ss, o); }
  if ((tid & 63) == 0) { sm[tid >> 6] = s; sm[4 + (tid >> 6)] = ss; }
  __syncthreads();
  const float S = sm[0] + sm[1] + sm[2] + sm[3];
  const float SS = sm[4] + sm[5] + sm[6] + sm[7];
  const float mu = S * (1.0f / EE);
  const float var = SS * (1.0f / EE) - mu * mu;
  const float inv = rsqrtf(var + 1e-5f);
  const float y0 = (x0 - mu) * inv * g[tid] + bta[tid];
  const float y1 = (x1 - mu) * inv * g[tid + 256] + bta[tid + 256];
  hout[base + tid] = y0;       hout[base + tid + 256] = y1;
  hbout[base + tid] = f2b(y0); hbout[base + tid + 256] = f2b(y1);
}

// ---------- LDS-tiled transpose-convert ----------
template<typename ST>
__global__ __launch_bounds__(256) void transposeT_kernel(
    u16* __restrict__ dst, const ST* __restrict__ src,
    int ldsrc, int lddst, Off3 dstz, Off3 srcz)
{
  __shared__ float t[32][33];
  const int z = blockIdx.z;
  const ST* s = src + off3(srcz, z);
  u16* d = dst + off3(dstz, z);
  const int r0 = blockIdx.x * 32, c0 = blockIdx.y * 32;
  const int tx = threadIdx.x & 31, ty = threadIdx.x >> 5;
  #pragma unroll
  for (int j = 0; j < 4; ++j) {
    const int r = ty + j * 8;
    t[r][tx] = tof(s[(long long)(r0 + r) * ldsrc + c0 + tx]);
  }
  __syncthreads();
  #pragma unroll
  for (int j = 0; j < 4; ++j) {
    const int c = ty + j * 8;
    d[(long long)(c0 + c) * lddst + r0 + tx] = f2b(t[tx][c]);
  }
}

// ---------- stack bq|bk|bv per layer ----------
__global__ __launch_bounds__(256) void biaspack_kernel(
    float* __restrict__ dst, const float* __restrict__ bq,
    const float* __restrict__ bk, const float* __restrict__ bv)
{
  const int i = blockIdx.x * 256 + threadIdx.x;
  if (i >= LL * 1536) return;
  const int l = i / 1536, j = i % 1536;
  dst[i] = (j < 512) ? bq[l * 512 + j]
         : (j < 1024) ? bk[l * 512 + j - 512]
                      : bv[l * 512 + j - 1024];
}

__global__ void finalize_loss(float* out) { out[0] = LAMBDA * (float)(LL * 32 * 1024); }

// ---------- host ----------
extern "C" void kernel_launch(void* const* d_in, const int* in_sizes, int n_in,
                              void* d_out, int out_size, void* d_ws, size_t ws_size,
                              hipStream_t stream)
{
  (void)in_sizes; (void)n_in; (void)out_size; (void)ws_size;
  const float* tok = (const float*)d_in[0];
  const float* pos = (const float*)d_in[1];
  const float* wq  = (const float*)d_in[2];
  const float* bq  = (const float*)d_in[3];
  const float* wk  = (const float*)d_in[4];
  const float* bk  = (const float*)d_in[5];
  const float* wv  = (const float*)d_in[6];
  const float* bv  = (const float*)d_in[7];
  const float* we  = (const float*)d_in[8];
  const float* be  = (const float*)d_in[9];
  const float* wd  = (const float*)d_in[10];
  const float* bd  = (const float*)d_in[11];
  const float* wo  = (const float*)d_in[12];
  const float* bo  = (const float*)d_in[13];
  const float* ln1g = (const float*)d_in[14];
  const float* ln1b = (const float*)d_in[15];
  const float* w1  = (const float*)d_in[16];
  const float* b1  = (const float*)d_in[17];
  const float* w2  = (const float*)d_in[18];
  const float* b2  = (const float*)d_in[19];
  const float* ln2g = (const float*)d_in[20];
  const float* ln2b = (const float*)d_in[21];
  const int*   x   = (const int*)d_in[22];

  char* ws = (char*)d_ws;
  size_t off = 0;
  auto alloc = [&](size_t bytes) { void* p = ws + off; off = (off + bytes + 255) & ~255ULL; return p; };

  u16*  wqkvT = (u16*)alloc((size_t)LL * 3 * 512 * 512 * 2);
  u16*  weT   = (u16*)alloc((size_t)LL * HH * T4 * TT * 2);
  u16*  wdT   = (u16*)alloc((size_t)LL * HH * TT * T4 * 2);
  u16*  woT   = (u16*)alloc((size_t)LL * EE * EE * 2);
  u16*  w1T   = (u16*)alloc((size_t)LL * FF * EE * 2);
  u16*  w2T   = (u16*)alloc((size_t)LL * EE * FF * 2);
  float* bqkv = (float*)alloc((size_t)LL * 1536 * 4);
  float* h_f  = (float*)alloc((size_t)BT * EE * 4);
  u16*  h_b   = (u16*)alloc((size_t)BT * EE * 2);
  u16*  q_b   = (u16*)alloc((size_t)BT * EE * 2);
  u16*  kT_b  = (u16*)alloc((size_t)32 * HD * TT * 2);
  u16*  vT_b  = (u16*)alloc((size_t)32 * HD * TT * 2);
  u16*  MT_b  = (u16*)alloc((size_t)32 * T4 * HD * 2);
  float* MT_part = (float*)alloc((size_t)4 * 32 * T4 * HD * 4);
  u16*  o_b   = (u16*)alloc((size_t)BT * EE * 2);
  u16*  attn_d = (u16*)alloc((size_t)BT * EE * 2);
  u16*  ff2_d  = (u16*)alloc((size_t)BT * EE * 2);
  u16*  ff1_b = (u16*)alloc((size_t)BT * FF * 2);
  u16*  o_part = (u16*)alloc((size_t)2 * BT * EE * 2);
  float* rs_part = (float*)alloc((size_t)2 * 32 * 1024 * 4);

  const Off3 Z1 = {0, 0, 1};

  embed_kernel<<<dim3(BT), 256, 0, stream>>>(tok, pos, x, h_f, h_b);
  biaspack_kernel<<<dim3((LL * 1536 + 255) / 256), 256, 0, stream>>>(bqkv, bq, bk, bv);

  transposeT_kernel<float><<<dim3(16, 2, 48), 256, 0, stream>>>(
      wqkvT,          wq, 64, 512, Off3{786432, 32768, 8}, Off3{32768, 0, 1});
  transposeT_kernel<float><<<dim3(16, 2, 48), 256, 0, stream>>>(
      wqkvT + 262144, wk, 64, 512, Off3{786432, 32768, 8}, Off3{32768, 0, 1});
  transposeT_kernel<float><<<dim3(16, 2, 48), 256, 0, stream>>>(
      wqkvT + 524288, wv, 64, 512, Off3{786432, 32768, 8}, Off3{32768, 0, 1});
  transposeT_kernel<float><<<dim3(32, 8, 48), 256, 0, stream>>>(
      weT, we, 256, 1024, Off3{262144, 0, 1}, Off3{262144, 0, 1});
  transposeT_kernel<float><<<dim3(8, 32, 48), 256, 0, stream>>>(
      wdT, wd, 1024, 256, Off3{262144, 0, 1}, Off3{262144, 0, 1});
  transposeT_kernel<float><<<dim3(16, 16, 6), 256, 0, stream>>>(
      woT, wo, 512, 512, Off3{262144, 0, 1}, Off3{262144, 0, 1});
  transposeT_kernel<float><<<dim3(16, 64, 6), 256, 0, stream>>>(
      w1T, w1, 2048, 512, Off3{1048576, 0, 1}, Off3{1048576, 0, 1});
  transposeT_kernel<float><<<dim3(64, 16, 6), 256, 0, stream>>>(
      w2T, w2, 512, 2048, Off3{1048576, 0, 1}, Off3{1048576, 0, 1});

  for (int l = 0; l < LL; ++l) {
    // --- fused q|k|v projection; q row-major, k/v transposed per head ---
    gemm_p<64, 128, true, 0, false, true><<<dim3(64, 12, 1), 256, 0, stream>>>(
        h_b, wqkvT + (size_t)l * 786432, q_b, bqkv + l * 1536, 1.0f,
        512, 512, 512, 512, Z1, Z1, Z1, Z1, 0, kT_b, vT_b);

    // --- MT[u][d] = sum_s we[s][u] k[s][d] : split-K x4 ---
    gemm_p<64, 64, false, 0, true, false><<<dim3(4, 4, 32), 256, 0, stream>>>(
        weT + (size_t)l * 2097152, kT_b, MT_part, nullptr, 1.0f,
        256, 1024, 1024, 64,
        Off3{0, 262144, 8}, Off3{65536, 0, 1}, Off3{16384, 0, 1}, Z1, 524288,
        nullptr, nullptr);
    mt_combine_kernel<<<dim3(2048), 256, 0, stream>>>(MT_part, MT_b);

    // --- fused tail: lat in-register; P = exp(sigmoid(lat@wd+bd)); bf16 partials ---
    attn_tail_kernel<<<dim3(1024), 128, 0, stream>>>(
        q_b, MT_b, be + (size_t)l * 2048, wdT + (size_t)l * 2097152,
        bd + (size_t)l * 8192, vT_b, o_part, rs_part);
    attn_combine_kernel<<<dim3(BT), 256, 0, stream>>>(o_part, rs_part, o_b);

    // --- attn out projection ---
    gemm_p<64, 64, true, 0, false, false><<<dim3(64, 8, 1), 256, 0, stream>>>(
        o_b, woT + (size_t)l * 262144, attn_d, bo + l * 512, 1.0f,
        512, 512, 512, 512, Z1, Z1, Z1, Z1, 0, nullptr, nullptr);

    addnorm_kernel<<<dim3(BT), 256, 0, stream>>>(h_f, attn_d, ln1g + l * 512, ln1b + l * 512, h_f, h_b);

    // --- FFN ---
    gemm_p<64, 128, true, 1, false, false><<<dim3(64, 16, 1), 256, 0, stream>>>(
        h_b, w1T + (size_t)l * 1048576, ff1_b, b1 + l * 2048, 1.0f,
        512, 512, 512, 2048, Z1, Z1, Z1, Z1, 0, nullptr, nullptr);
    gemm_p<64, 64, true, 1, false, false><<<dim3(64, 8, 1), 256, 0, stream>>>(
        ff1_b, w2T + (size_t)l * 1048576, ff2_d, b2 + l * 512, 1.0f,
        2048, 2048, 2048, 512, Z1, Z1, Z1, Z1, 0, nullptr, nullptr);

    float* hout = (l == LL - 1) ? (float*)d_out : h_f;
    addnorm_kernel<<<dim3(BT), 256, 0, stream>>>(h_f, ff2_d, ln2g + l * 512, ln2b + l * 512, hout, h_b);
  }

  finalize_loss<<<1, 1, 0, stream>>>((float*)d_out + (size_t)BT * EE);
}